// Round 1
// baseline (656.449 us; speedup 1.0000x reference)
//
#include <hip/hip_runtime.h>
#include <math.h>

// Problem constants
#define B_    8
#define C_    64     // cin
#define H_    128
#define W_    128
#define HS    64     // subband spatial
#define WS    64
#define K_    4      // attention experts
#define SUB   4      // subbands: ll, h0, h1, hh
#define COUT_ 64

// Conv kernel tiling
#define TILE  32     // spatial tile (subband space)
#define COG   4      // couts per block
#define CICH  2      // cin per LDS chunk
#define HALO  34     // TILE + 2
#define HPAD  36     // padded row stride

// Workspace layout (floats):
//   kmix  [B][SUB][COUT][C][9]            : 1,179,648
//   sums  [B][C][SUB]                     : 2,048
//   att   [B][SUB][K]                     : 128
//   feats [SUB][B][C][64][64]             : 8,388,608
#define WS_KMIX   0
#define WS_SUMS   (1179648)
#define WS_ATT    (1179648 + 2048)
#define WS_FEATS  (1179648 + 2048 + 128)

// ---------------------------------------------------------------------------
// K1: Haar DWT (x -> 4 subbands) + per-(b,c,sub) spatial sums for attention
// grid: 512 blocks (b*c), 256 threads
// ---------------------------------------------------------------------------
__global__ __launch_bounds__(256)
void dwt_sums_kernel(const float* __restrict__ x, float* __restrict__ feats,
                     float* __restrict__ sums) {
    int bc = blockIdx.x;               // b*64 + c
    const float* img = x + (size_t)bc * (H_ * W_);
    float* f0 = feats + 0 * (size_t)(B_ * C_ * HS * WS) + (size_t)bc * (HS * WS);
    float* f1 = feats + 1 * (size_t)(B_ * C_ * HS * WS) + (size_t)bc * (HS * WS);
    float* f2 = feats + 2 * (size_t)(B_ * C_ * HS * WS) + (size_t)bc * (HS * WS);
    float* f3 = feats + 3 * (size_t)(B_ * C_ * HS * WS) + (size_t)bc * (HS * WS);

    float s0 = 0.f, s1 = 0.f, s2 = 0.f, s3 = 0.f;
    int t = threadIdx.x;
    for (int i = t; i < HS * WS; i += 256) {
        int y = i >> 6, xx = i & 63;
        const float2* row0 = (const float2*)(img + (size_t)(2 * y) * W_);
        const float2* row1 = (const float2*)(img + (size_t)(2 * y + 1) * W_);
        float2 p = row0[xx];           // a = x[2y,2x], b = x[2y,2x+1]
        float2 q = row1[xx];           // c = x[2y+1,2x], d = x[2y+1,2x+1]
        float a = p.x, b = p.y, c = q.x, d = q.y;
        float ll = (a + b + c + d) * 0.5f;
        float h0 = (a + b - c - d) * 0.5f;
        float h1 = (a - b + c - d) * 0.5f;
        float hh = (a - b - c + d) * 0.5f;
        f0[i] = ll; f1[i] = h0; f2[i] = h1; f3[i] = hh;
        s0 += ll; s1 += h0; s2 += h1; s3 += hh;
    }
    // wave (64-lane) reduction
    #pragma unroll
    for (int off = 32; off > 0; off >>= 1) {
        s0 += __shfl_down(s0, off);
        s1 += __shfl_down(s1, off);
        s2 += __shfl_down(s2, off);
        s3 += __shfl_down(s3, off);
    }
    __shared__ float red[4][4];
    int lane = t & 63, wv = t >> 6;
    if (lane == 0) { red[wv][0] = s0; red[wv][1] = s1; red[wv][2] = s2; red[wv][3] = s3; }
    __syncthreads();
    if (t < 4) {
        float s = red[0][t] + red[1][t] + red[2][t] + red[3][t];
        sums[(size_t)bc * 4 + t] = s;
    }
}

// ---------------------------------------------------------------------------
// K2: attention logits + softmax.  1 block, 128 threads = (b, sub, k)
// ---------------------------------------------------------------------------
__global__ __launch_bounds__(128)
void attn_kernel(const float* __restrict__ sums, const float* __restrict__ attn_w,
                 const float* __restrict__ attn_b, float* __restrict__ att) {
    int t = threadIdx.x;               // 0..127
    int b = t >> 4, sub = (t >> 2) & 3, k = t & 3;
    float acc = 0.f;
    for (int c = 0; c < C_; ++c)
        acc += attn_w[k * C_ + c] * sums[((size_t)b * C_ + c) * 4 + sub];
    float logit = acc * (1.0f / (HS * WS)) + attn_b[k];
    // softmax over k (groups of 4 contiguous lanes, within one wave)
    float m = logit;
    m = fmaxf(m, __shfl_xor(m, 1));
    m = fmaxf(m, __shfl_xor(m, 2));
    float e = expf(logit - m);
    float s = e;
    s += __shfl_xor(s, 1);
    s += __shfl_xor(s, 2);
    att[t] = e / s;                    // layout [b][sub][k] == t
}

// ---------------------------------------------------------------------------
// K3: per-sample kernel mixing: kmix[b,sub,o,i,uv] = sum_k att[b,sub,k]*wt[k,sub,o,i,uv]
// ---------------------------------------------------------------------------
__global__ __launch_bounds__(256)
void mix_kernel(const float* __restrict__ wt, const float* __restrict__ att,
                float* __restrict__ kmix) {
    int idx = blockIdx.x * 256 + threadIdx.x;
    // total = B*SUB*COUT*C*9 = 1,179,648 (exactly 4608*256)
    int uv = idx % 9;
    int rest = idx / 9;                // ((b*4+sub)*64+o)*64+i
    int i = rest & 63;
    int rest2 = rest >> 6;
    int o = rest2 & 63;
    int rest3 = rest2 >> 6;            // b*4+sub
    int sub = rest3 & 3;
    const float* a4 = att + (size_t)rest3 * 4;
    const size_t kstride = (size_t)SUB * COUT_ * C_ * 9;  // 147456
    size_t base = (((size_t)sub * COUT_ + o) * C_ + i) * 9 + uv;
    float v = a4[0] * wt[base]
            + a4[1] * wt[base + kstride]
            + a4[2] * wt[base + 2 * kstride]
            + a4[3] * wt[base + 3 * kstride];
    kmix[idx] = v;
}

// ---------------------------------------------------------------------------
// K4: fused 4-subband dynamic conv (3x3, pad 1) + Haar IDWT epilogue.
// grid: (tiles=4, cg=16, b=8) = 512 blocks, 256 threads.
// Each thread: 2x2 subband pixels x COG couts x 4 subbands.
// ---------------------------------------------------------------------------
__global__ __launch_bounds__(256)
void conv_idwt_kernel(const float* __restrict__ feats, const float* __restrict__ kmix,
                      float* __restrict__ out) {
    __shared__ float sfeat[SUB * CICH][HALO * HPAD];   // 8 x 1224 floats
    __shared__ float sw[SUB * COG * CICH * 12];        // 384 floats (uv padded 9->12)

    int tile = blockIdx.x;             // 0..3
    int cg   = blockIdx.y;             // 0..15
    int b    = blockIdx.z;             // 0..7
    int ty0 = (tile >> 1) * TILE;
    int tx0 = (tile & 1) * TILE;
    int t = threadIdx.x;
    int qy = t >> 4, qx = t & 15;      // 16x16 threads, each 2x2 px

    float acc[SUB][COG][2][2];
    #pragma unroll
    for (int s = 0; s < SUB; ++s)
        #pragma unroll
        for (int co = 0; co < COG; ++co) {
            acc[s][co][0][0] = 0.f; acc[s][co][0][1] = 0.f;
            acc[s][co][1][0] = 0.f; acc[s][co][1][1] = 0.f;
        }

    const size_t subplane = (size_t)B_ * C_ * HS * WS;

    for (int ci0 = 0; ci0 < C_; ci0 += CICH) {
        __syncthreads();   // protect LDS from previous iteration's readers
        // ---- stage feature halo tiles: 8 planes x 34x34 ----
        for (int e = t; e < SUB * CICH * (HALO * HALO); e += 256) {
            int plane = e / (HALO * HALO);
            int off = e - plane * (HALO * HALO);
            int r = off / HALO;
            int cc = off - r * HALO;
            int sub = plane >> 1;      // plane = sub*CICH + ci
            int ci = plane & 1;
            int gy = ty0 - 1 + r;
            int gx = tx0 - 1 + cc;
            float v = 0.f;
            if ((unsigned)gy < 64u && (unsigned)gx < 64u)
                v = feats[(size_t)sub * subplane
                          + ((size_t)b * C_ + (ci0 + ci)) * (HS * WS)
                          + gy * WS + gx];
            sfeat[plane][r * HPAD + cc] = v;
        }
        // ---- stage weights: [sub][co][ci][uv(9, padded 12)] ----
        for (int e = t; e < SUB * COG * CICH * 9; e += 256) {
            int sub = e / (COG * CICH * 9);
            int r = e - sub * (COG * CICH * 9);
            int co = r / (CICH * 9);
            int r2 = r - co * (CICH * 9);
            int ci = r2 / 9;
            int uv = r2 - ci * 9;
            sw[((sub * COG + co) * CICH + ci) * 12 + uv] =
                kmix[((((size_t)b * SUB + sub) * COUT_ + (cg * COG + co)) * C_
                      + (ci0 + ci)) * 9 + uv];
        }
        __syncthreads();
        // ---- compute ----
        #pragma unroll
        for (int ci = 0; ci < CICH; ++ci) {
            #pragma unroll
            for (int sub = 0; sub < SUB; ++sub) {
                int plane = sub * CICH + ci;
                float f[4][4];
                #pragma unroll
                for (int r = 0; r < 4; ++r) {
                    const float2* fp =
                        (const float2*)&sfeat[plane][(2 * qy + r) * HPAD + 2 * qx];
                    float2 u0 = fp[0], u1 = fp[1];
                    f[r][0] = u0.x; f[r][1] = u0.y; f[r][2] = u1.x; f[r][3] = u1.y;
                }
                #pragma unroll
                for (int co = 0; co < COG; ++co) {
                    const float4* wq =
                        (const float4*)&sw[((sub * COG + co) * CICH + ci) * 12];
                    float4 w0 = wq[0], w1 = wq[1], w2 = wq[2];
                    float wv[9] = {w0.x, w0.y, w0.z, w0.w,
                                   w1.x, w1.y, w1.z, w1.w, w2.x};
                    #pragma unroll
                    for (int sy = 0; sy < 2; ++sy)
                        #pragma unroll
                        for (int sx = 0; sx < 2; ++sx)
                            #pragma unroll
                            for (int dy = 0; dy < 3; ++dy)
                                #pragma unroll
                                for (int dx = 0; dx < 3; ++dx)
                                    acc[sub][co][sy][sx] =
                                        fmaf(f[sy + dy][sx + dx], wv[dy * 3 + dx],
                                             acc[sub][co][sy][sx]);
                }
            }
        }
    }

    // ---- IDWT epilogue: coalesced float4 stores ----
    int oyb = ty0 + 2 * qy;            // subband-space base row
    int oxb = tx0 + 2 * qx;            // subband-space base col
    #pragma unroll
    for (int co = 0; co < COG; ++co) {
        int oc = cg * COG + co;
        #pragma unroll
        for (int sy = 0; sy < 2; ++sy) {
            float av[2], bv[2], cv[2], dv[2];
            #pragma unroll
            for (int sx = 0; sx < 2; ++sx) {
                float ll = acc[0][co][sy][sx];
                float h0 = acc[1][co][sy][sx];
                float h1 = acc[2][co][sy][sx];
                float hh = acc[3][co][sy][sx];
                av[sx] = (ll + h0 + h1 + hh) * 0.5f;
                bv[sx] = (ll + h0 - h1 - hh) * 0.5f;
                cv[sx] = (ll - h0 + h1 - hh) * 0.5f;
                dv[sx] = (ll - h0 - h1 + hh) * 0.5f;
            }
            size_t Y = (size_t)2 * (oyb + sy);
            size_t rowbase = ((size_t)(b * COUT_ + oc) * H_ + Y) * W_ + 2 * oxb;
            *(float4*)(out + rowbase)       = make_float4(av[0], bv[0], av[1], bv[1]);
            *(float4*)(out + rowbase + W_)  = make_float4(cv[0], dv[0], cv[1], dv[1]);
        }
    }
}

// ---------------------------------------------------------------------------
extern "C" void kernel_launch(void* const* d_in, const int* in_sizes, int n_in,
                              void* d_out, int out_size, void* d_ws, size_t ws_size,
                              hipStream_t stream) {
    const float* x  = (const float*)d_in[0];
    const float* wt = (const float*)d_in[1];
    const float* aw = (const float*)d_in[2];
    const float* ab = (const float*)d_in[3];
    float* out = (float*)d_out;
    float* ws  = (float*)d_ws;

    float* kmix  = ws + WS_KMIX;
    float* sums  = ws + WS_SUMS;
    float* att   = ws + WS_ATT;
    float* feats = ws + WS_FEATS;

    hipLaunchKernelGGL(dwt_sums_kernel, dim3(B_ * C_), dim3(256), 0, stream,
                       x, feats, sums);
    hipLaunchKernelGGL(attn_kernel, dim3(1), dim3(128), 0, stream,
                       sums, aw, ab, att);
    hipLaunchKernelGGL(mix_kernel, dim3(4608), dim3(256), 0, stream,
                       wt, att, kmix);
    hipLaunchKernelGGL(conv_idwt_kernel, dim3(4, 16, 8), dim3(256), 0, stream,
                       feats, kmix, out);
}

// Round 2
// 140.435 us; speedup vs baseline: 4.6744x; 4.6744x over previous
//
#include <hip/hip_runtime.h>
#include <hip/hip_bf16.h>
#include <math.h>

// Shapes: x(8,64,128,128) f32; wt(4,4,64,64,3,3) f32; attn_w(4,64); attn_b(4)
// Subband space: 64x64, 4 subbands, 64 cin, 64 cout.

typedef __bf16 bf16x8 __attribute__((ext_vector_type(8)));
typedef float f32x4 __attribute__((ext_vector_type(4)));

__device__ __forceinline__ bf16x8 as_bf16x8(uint4 u) {
    union { uint4 a; bf16x8 b; } c; c.a = u; return c.b;
}
__device__ __forceinline__ unsigned short bf16bits(float f) {
    __hip_bfloat16 h = __float2bfloat16(f);
    union { __hip_bfloat16 h; unsigned short u; } c; c.h = h; return c.u;
}

// ---------------------------------------------------------------------------
// K1: Haar DWT -> bf16 feats[b][sub][y][x][c] (channel-last) + attention sums
// grid (64 y, 8 b), 256 threads. LDS transpose [sub][x][72c-pad].
// ---------------------------------------------------------------------------
__global__ __launch_bounds__(256)
void dwt_kernel(const float* __restrict__ x, unsigned short* __restrict__ feats,
                float* __restrict__ sums) {
    __shared__ uint4 sT[2304];                     // 4 sub * 64 x * 9 chunks (72 bf16)
    unsigned short* sTu = (unsigned short*)sT;
    int y = blockIdx.x, b = blockIdx.y;
    int t = threadIdx.x;
    int c = t >> 2, q = t & 3;

    const float4* r0 = (const float4*)x + ((size_t)(b * 64 + c) * 128 + 2 * y) * 32 + q * 8;
    const float4* r1 = r0 + 32;                    // next image row (128 f32 = 32 f4)

    float s0 = 0.f, s1 = 0.f, s2 = 0.f, s3 = 0.f;
    #pragma unroll
    for (int i = 0; i < 8; ++i) {
        float4 p = r0[i], qq = r1[i];
        int xo = q * 16 + 2 * i;
        {
            float a = p.x, bb = p.y, cc = qq.x, dd = qq.y;
            float ll = (a + bb + cc + dd) * 0.5f, h0 = (a + bb - cc - dd) * 0.5f;
            float h1 = (a - bb + cc - dd) * 0.5f, hh = (a - bb - cc + dd) * 0.5f;
            s0 += ll; s1 += h0; s2 += h1; s3 += hh;
            sTu[0 * 4608 + xo * 72 + c] = bf16bits(ll);
            sTu[1 * 4608 + xo * 72 + c] = bf16bits(h0);
            sTu[2 * 4608 + xo * 72 + c] = bf16bits(h1);
            sTu[3 * 4608 + xo * 72 + c] = bf16bits(hh);
        }
        {
            float a = p.z, bb = p.w, cc = qq.z, dd = qq.w;
            float ll = (a + bb + cc + dd) * 0.5f, h0 = (a + bb - cc - dd) * 0.5f;
            float h1 = (a - bb + cc - dd) * 0.5f, hh = (a - bb - cc + dd) * 0.5f;
            s0 += ll; s1 += h0; s2 += h1; s3 += hh;
            sTu[0 * 4608 + (xo + 1) * 72 + c] = bf16bits(ll);
            sTu[1 * 4608 + (xo + 1) * 72 + c] = bf16bits(h0);
            sTu[2 * 4608 + (xo + 1) * 72 + c] = bf16bits(h1);
            sTu[3 * 4608 + (xo + 1) * 72 + c] = bf16bits(hh);
        }
    }
    // reduce over q (4 consecutive lanes share c), then atomics into sums[b*64+c][sub]
    s0 += __shfl_xor(s0, 1); s0 += __shfl_xor(s0, 2);
    s1 += __shfl_xor(s1, 1); s1 += __shfl_xor(s1, 2);
    s2 += __shfl_xor(s2, 1); s2 += __shfl_xor(s2, 2);
    s3 += __shfl_xor(s3, 1); s3 += __shfl_xor(s3, 2);
    if (q == 0) {
        float* sp = sums + (size_t)(b * 64 + c) * 4;
        atomicAdd(sp + 0, s0); atomicAdd(sp + 1, s1);
        atomicAdd(sp + 2, s2); atomicAdd(sp + 3, s3);
    }
    __syncthreads();
    // phase 2: coalesced channel-last global writes (16B/lane)
    uint4* fch = (uint4*)feats;
    for (int e = t; e < 2048; e += 256) {
        int s = e >> 9, xx = (e >> 3) & 63, ck = e & 7;
        fch[(size_t)((b * 4 + s) * 64 + y) * 512 + xx * 8 + ck] = sT[s * 576 + xx * 9 + ck];
    }
}

// ---------------------------------------------------------------------------
// K2: attention logits + softmax. 1 block, 128 threads = (b, sub, k)
// ---------------------------------------------------------------------------
__global__ __launch_bounds__(128)
void attn_kernel(const float* __restrict__ sums, const float* __restrict__ attn_w,
                 const float* __restrict__ attn_b, float* __restrict__ att) {
    int t = threadIdx.x;               // 0..127
    int b = t >> 4, sub = (t >> 2) & 3, k = t & 3;
    float acc = 0.f;
    for (int c = 0; c < 64; ++c)
        acc += attn_w[k * 64 + c] * sums[((size_t)b * 64 + c) * 4 + sub];
    float logit = acc * (1.0f / 4096.0f) + attn_b[k];
    float m = logit;
    m = fmaxf(m, __shfl_xor(m, 1));
    m = fmaxf(m, __shfl_xor(m, 2));
    float e = expf(logit - m);
    float s = e;
    s += __shfl_xor(s, 1);
    s += __shfl_xor(s, 2);
    att[t] = e / s;                    // [b][sub][k]
}

// ---------------------------------------------------------------------------
// K3: kernel mixing -> bf16 wmix[b][sub][tap][co][ci]
// grid (8, 9 taps, 32 b*sub), 256 threads, 2 elements/thread
// ---------------------------------------------------------------------------
__global__ __launch_bounds__(256)
void mix_kernel(const float* __restrict__ wt, const float* __restrict__ att,
                unsigned short* __restrict__ wmix) {
    int tap = blockIdx.y, bz = blockIdx.z;
    int sub = bz & 3;
    int flat2 = blockIdx.x * 512 + threadIdx.x * 2;   // (co*64+ci), even
    int co = flat2 >> 6, ci = flat2 & 63;
    const float* a4 = att + (size_t)bz * 4;
    const size_t ks = 147456;                          // k-stride in wt
    size_t base = (((size_t)sub * 64 + co) * 64 + ci) * 9 + tap;
    float v0 = a4[0] * wt[base] + a4[1] * wt[base + ks]
             + a4[2] * wt[base + 2 * ks] + a4[3] * wt[base + 3 * ks];
    float v1 = a4[0] * wt[base + 9] + a4[1] * wt[base + ks + 9]
             + a4[2] * wt[base + 2 * ks + 9] + a4[3] * wt[base + 3 * ks + 9];
    ushort2 o; o.x = bf16bits(v0); o.y = bf16bits(v1);
    *(ushort2*)(wmix + (size_t)bz * 36864 + tap * 4096 + flat2) = o;
}

// ---------------------------------------------------------------------------
// K4: MFMA implicit-GEMM 3x3 conv per (b,sub), tap-decomposed.
// grid (16 tiles, 4 sub, 8 b), 256 threads (4 waves).
// Block: 16x16 px tile (M=256), N=64 couts, K=64ci in 2 chunks of 32.
// Wave w: y rows 4w..4w+3 (M-subtiles r), all 64 couts (N-subtiles nn).
// Out: conv_out[b][sub][y][x][co] bf16.
// ---------------------------------------------------------------------------
__global__ __launch_bounds__(256, 2)
void conv_kernel(const unsigned short* __restrict__ feats,
                 const unsigned short* __restrict__ wmix,
                 unsigned short* __restrict__ conv_out) {
    __shared__ uint4 sA[1296];         // [18 py][18 px][4 kg] : 18x18 halo x 32 ci
    __shared__ uint4 sW[2304];         // [9 tap][64 co][4 kg] : 32 ci
    int tile = blockIdx.x, sub = blockIdx.y, b = blockIdx.z;
    int y0 = (tile >> 2) * 16, x0 = (tile & 3) * 16;
    int t = threadIdx.x, w = t >> 6, l = t & 63;
    int l16 = l & 15, kg = l >> 4;
    const uint4* fch = (const uint4*)feats + (size_t)(b * 4 + sub) * 32768;
    const uint4* wch = (const uint4*)wmix + (size_t)(b * 4 + sub) * 4608;

    f32x4 acc[4][4];
    #pragma unroll
    for (int r = 0; r < 4; ++r)
        #pragma unroll
        for (int nn = 0; nn < 4; ++nn)
            acc[r][nn] = (f32x4){0.f, 0.f, 0.f, 0.f};

    #pragma unroll
    for (int ck8 = 0; ck8 < 8; ck8 += 4) {   // ci chunk offset in 16B units: {0,4}
        __syncthreads();
        // stage A halo tile (zero-fill out of range)
        for (int e = t; e < 1296; e += 256) {
            int py = e / 72, rr = e - py * 72, px = rr >> 2, g = rr & 3;
            int gy = y0 - 1 + py, gx = x0 - 1 + px;
            uint4 v = make_uint4(0u, 0u, 0u, 0u);
            if ((unsigned)gy < 64u && (unsigned)gx < 64u)
                v = fch[(gy * 64 + gx) * 8 + ck8 + g];
            sA[e] = v;
        }
        // stage weights: all 9 taps, this ci chunk
        for (int e = t; e < 2304; e += 256) {
            int tap = e >> 8, co = (e >> 2) & 63, g = e & 3;
            sW[e] = wch[tap * 512 + co * 8 + ck8 + g];
        }
        __syncthreads();
        #pragma unroll
        for (int tap = 0; tap < 9; ++tap) {
            int dy = tap / 3, dx = tap - dy * 3;
            bf16x8 bfr[4];
            #pragma unroll
            for (int nn = 0; nn < 4; ++nn)
                bfr[nn] = as_bf16x8(sW[tap * 256 + (nn * 16 + l16) * 4 + kg]);
            #pragma unroll
            for (int r = 0; r < 4; ++r) {
                bf16x8 af = as_bf16x8(sA[((w * 4 + r + dy) * 18 + l16 + dx) * 4 + kg]);
                #pragma unroll
                for (int nn = 0; nn < 4; ++nn)
                    acc[r][nn] = __builtin_amdgcn_mfma_f32_16x16x32_bf16(
                        af, bfr[nn], acc[r][nn], 0, 0, 0);
            }
        }
    }
    // epilogue: D row=(lane>>4)*4+reg is the x-offset, col=lane&15 is cout
    size_t obase = (size_t)(b * 4 + sub) * 262144;
    #pragma unroll
    for (int r = 0; r < 4; ++r) {
        int yy = y0 + w * 4 + r;
        #pragma unroll
        for (int nn = 0; nn < 4; ++nn) {
            int co = nn * 16 + l16;
            #pragma unroll
            for (int j = 0; j < 4; ++j) {
                int xx = x0 + kg * 4 + j;
                conv_out[obase + ((size_t)yy * 64 + xx) * 64 + co] = bf16bits(acc[r][nn][j]);
            }
        }
    }
}

// ---------------------------------------------------------------------------
// K5: Haar IDWT: conv_out[b][sub][y][x][co] bf16 -> out[b][co][Y][X] f32
// grid (64 y, 8 b), 256 threads. LDS transpose.
// ---------------------------------------------------------------------------
__global__ __launch_bounds__(256)
void idwt_kernel(const unsigned short* __restrict__ conv_out,
                 float* __restrict__ out) {
    __shared__ uint4 sT[2304];         // [sub][x][9 chunks] (8 used = 64 c)
    int y = blockIdx.x, b = blockIdx.y;
    int t = threadIdx.x;
    const uint4* cch = (const uint4*)conv_out;
    for (int e = t; e < 2048; e += 256) {
        int s = e >> 9, xx = (e >> 3) & 63, ck = e & 7;
        sT[s * 576 + xx * 9 + ck] = cch[(size_t)(b * 4 + s) * 32768 + y * 512 + xx * 8 + ck];
    }
    __syncthreads();
    int xx = t & 63, cw = t >> 6;
    #pragma unroll
    for (int half = 0; half < 2; ++half) {
        int ckk = half * 4 + cw;       // c chunk 0..7
        bf16x8 v0 = as_bf16x8(sT[0 * 576 + xx * 9 + ckk]);
        bf16x8 v1 = as_bf16x8(sT[1 * 576 + xx * 9 + ckk]);
        bf16x8 v2 = as_bf16x8(sT[2 * 576 + xx * 9 + ckk]);
        bf16x8 v3 = as_bf16x8(sT[3 * 576 + xx * 9 + ckk]);
        #pragma unroll
        for (int j = 0; j < 8; ++j) {
            int c = ckk * 8 + j;
            float ll = (float)v0[j], h0 = (float)v1[j];
            float h1 = (float)v2[j], hh = (float)v3[j];
            float a = (ll + h0 + h1 + hh) * 0.5f;
            float bb = (ll + h0 - h1 - hh) * 0.5f;
            float cc = (ll - h0 + h1 - hh) * 0.5f;
            float dd = (ll - h0 - h1 + hh) * 0.5f;
            float2* o0 = (float2*)out + ((size_t)(b * 64 + c) * 128 + 2 * y) * 64 + xx;
            o0[0]  = make_float2(a, bb);
            o0[64] = make_float2(cc, dd);
        }
    }
}

// ---------------------------------------------------------------------------
extern "C" void kernel_launch(void* const* d_in, const int* in_sizes, int n_in,
                              void* d_out, int out_size, void* d_ws, size_t ws_size,
                              hipStream_t stream) {
    const float* x  = (const float*)d_in[0];
    const float* wt = (const float*)d_in[1];
    const float* aw = (const float*)d_in[2];
    const float* ab = (const float*)d_in[3];
    float* out = (float*)d_out;
    char* ws = (char*)d_ws;

    float* sums              = (float*)ws;                        // 8192 B
    float* att               = (float*)(ws + 8192);               // 512 B
    unsigned short* feats    = (unsigned short*)(ws + 8704);      // 16,777,216 B
    unsigned short* wmix     = (unsigned short*)(ws + 8704 + 16777216);        // 2,359,296 B
    unsigned short* conv_out = (unsigned short*)(ws + 8704 + 16777216 + 2359296); // 16,777,216 B

    hipMemsetAsync(sums, 0, 8192, stream);
    hipLaunchKernelGGL(dwt_kernel, dim3(64, 8), dim3(256), 0, stream, x, feats, sums);
    hipLaunchKernelGGL(attn_kernel, dim3(1), dim3(128), 0, stream, sums, aw, ab, att);
    hipLaunchKernelGGL(mix_kernel, dim3(8, 9, 32), dim3(256), 0, stream, wt, att, wmix);
    hipLaunchKernelGGL(conv_kernel, dim3(16, 4, 8), dim3(256), 0, stream, feats, wmix, conv_out);
    hipLaunchKernelGGL(idwt_kernel, dim3(64, 8), dim3(256), 0, stream, conv_out, out);
}

// Round 3
// 134.376 us; speedup vs baseline: 4.8852x; 1.0451x over previous
//
#include <hip/hip_runtime.h>
#include <hip/hip_bf16.h>
#include <math.h>

// Shapes: x(8,64,128,128) f32; wt(4,4,64,64,3,3) f32; attn_w(4,64); attn_b(4)
// Subband space: 64x64, 4 subbands, 64 cin, 64 cout.

typedef __bf16 bf16x8 __attribute__((ext_vector_type(8)));
typedef float f32x4 __attribute__((ext_vector_type(4)));

__device__ __forceinline__ bf16x8 as_bf16x8(uint4 u) {
    union { uint4 a; bf16x8 b; } c; c.a = u; return c.b;
}
__device__ __forceinline__ unsigned short bf16bits(float f) {
    __hip_bfloat16 h = __float2bfloat16(f);
    union { __hip_bfloat16 h; unsigned short u; } c; c.h = h; return c.u;
}

// ---------------------------------------------------------------------------
// K1: Haar DWT -> bf16 feats[b][sub][y][x][c] (channel-last) + attention sums
// grid (64 y, 8 b), 256 threads. Lane quad reads 64B contiguous (coalesced).
// LDS transpose [sub][x][72c-pad]; bank = (8q + c/2) % 32 -> 2-way (free).
// ---------------------------------------------------------------------------
__global__ __launch_bounds__(256)
void dwt_kernel(const float* __restrict__ x, unsigned short* __restrict__ feats,
                float* __restrict__ sums) {
    __shared__ uint4 sT[2304];                     // 4 sub * 64 x * 9 chunks (72 bf16)
    unsigned short* sTu = (unsigned short*)sT;
    int y = blockIdx.x, b = blockIdx.y;
    int t = threadIdx.x;
    int c = t >> 2, q = t & 3;

    const float4* r0 = (const float4*)x + ((size_t)(b * 64 + c) * 128 + 2 * y) * 32;
    const float4* r1 = r0 + 32;                    // next image row

    float s0 = 0.f, s1 = 0.f, s2 = 0.f, s3 = 0.f;
    #pragma unroll
    for (int i = 0; i < 8; ++i) {
        int f = i * 4 + q;                         // quad covers 4 consecutive float4
        float4 p = r0[f], qq = r1[f];
        int xo = 2 * f;
        {
            float a = p.x, bb = p.y, cc = qq.x, dd = qq.y;
            float ll = (a + bb + cc + dd) * 0.5f, h0 = (a + bb - cc - dd) * 0.5f;
            float h1 = (a - bb + cc - dd) * 0.5f, hh = (a - bb - cc + dd) * 0.5f;
            s0 += ll; s1 += h0; s2 += h1; s3 += hh;
            sTu[0 * 4608 + xo * 72 + c] = bf16bits(ll);
            sTu[1 * 4608 + xo * 72 + c] = bf16bits(h0);
            sTu[2 * 4608 + xo * 72 + c] = bf16bits(h1);
            sTu[3 * 4608 + xo * 72 + c] = bf16bits(hh);
        }
        {
            float a = p.z, bb = p.w, cc = qq.z, dd = qq.w;
            float ll = (a + bb + cc + dd) * 0.5f, h0 = (a + bb - cc - dd) * 0.5f;
            float h1 = (a - bb + cc - dd) * 0.5f, hh = (a - bb - cc + dd) * 0.5f;
            s0 += ll; s1 += h0; s2 += h1; s3 += hh;
            sTu[0 * 4608 + (xo + 1) * 72 + c] = bf16bits(ll);
            sTu[1 * 4608 + (xo + 1) * 72 + c] = bf16bits(h0);
            sTu[2 * 4608 + (xo + 1) * 72 + c] = bf16bits(h1);
            sTu[3 * 4608 + (xo + 1) * 72 + c] = bf16bits(hh);
        }
    }
    // reduce over q (4 consecutive lanes share c), then atomics into sums[b*64+c][sub]
    s0 += __shfl_xor(s0, 1); s0 += __shfl_xor(s0, 2);
    s1 += __shfl_xor(s1, 1); s1 += __shfl_xor(s1, 2);
    s2 += __shfl_xor(s2, 1); s2 += __shfl_xor(s2, 2);
    s3 += __shfl_xor(s3, 1); s3 += __shfl_xor(s3, 2);
    if (q == 0) {
        float* sp = sums + (size_t)(b * 64 + c) * 4;
        atomicAdd(sp + 0, s0); atomicAdd(sp + 1, s1);
        atomicAdd(sp + 2, s2); atomicAdd(sp + 3, s3);
    }
    __syncthreads();
    // coalesced channel-last global writes (16B/lane)
    uint4* fch = (uint4*)feats;
    for (int e = t; e < 2048; e += 256) {
        int s = e >> 9, xx = (e >> 3) & 63, ck = e & 7;
        fch[(size_t)((b * 4 + s) * 64 + y) * 512 + xx * 8 + ck] = sT[s * 576 + xx * 9 + ck];
    }
}

// ---------------------------------------------------------------------------
// K2: fused attention + kernel mixing -> bf16 wmix[b][sub][tap][co][ci]
// grid (64 co, 4 sub), 256 threads. Coalesced wt staging, LDS transpose.
// ---------------------------------------------------------------------------
__global__ __launch_bounds__(256)
void mix_kernel(const float* __restrict__ wt, const float* __restrict__ attn_w,
                const float* __restrict__ attn_b, const float* __restrict__ sums,
                unsigned short* __restrict__ wmix) {
    __shared__ float sLw[4][576];       // [k][ci*9+tap]
    __shared__ float satt[8][4];        // [b][k]
    int co = blockIdx.x, sub = blockIdx.y;
    int t = threadIdx.x;

    // attention for all 8 b of this sub (first 32 lanes of wave 0)
    if (t < 32) {
        int b = t >> 2, k = t & 3;
        float acc = 0.f;
        #pragma unroll 8
        for (int c = 0; c < 64; ++c)
            acc += attn_w[k * 64 + c] * sums[((size_t)(b * 64 + c) << 2) + sub];
        float logit = acc * (1.0f / 4096.0f) + attn_b[k];
        float m = fmaxf(logit, __shfl_xor(logit, 1));
        m = fmaxf(m, __shfl_xor(m, 2));
        float e = expf(logit - m);
        float s = e + __shfl_xor(e, 1);
        s += __shfl_xor(s, 2);
        satt[b][k] = e / s;
    }
    // stage wt[k][sub][co][:][:] for k=0..3 (contiguous 576-f32 runs, coalesced)
    for (int e = t; e < 2304; e += 256) {
        int k = e / 576, r = e - k * 576;
        sLw[k][r] = wt[((size_t)(k * 4 + sub) * 64 + co) * 576 + r];
    }
    __syncthreads();
    // produce all 8 b: 18 outputs/thread, 128B-coalesced bf16 writes.
    // LDS reads stride 9 over ci: 9 coprime 32 -> conflict-free.
    #pragma unroll
    for (int j = 0; j < 18; ++j) {
        int idx = j * 256 + t;                  // 64-lane runs stay within one (b,tap)
        int b = idx / 576;
        int r = idx - b * 576;
        int tap = r >> 6, ci = r & 63;
        int wi = ci * 9 + tap;
        float v = satt[b][0] * sLw[0][wi] + satt[b][1] * sLw[1][wi]
                + satt[b][2] * sLw[2][wi] + satt[b][3] * sLw[3][wi];
        wmix[((size_t)(b * 4 + sub) * 9 + tap) * 4096 + co * 64 + ci] = bf16bits(v);
    }
}

// ---------------------------------------------------------------------------
// K3: MFMA implicit-GEMM 3x3 conv per (b,sub), tap-decomposed.
// grid (16 tiles, 4 sub, 8 b), 256 threads (4 waves).
// Block: 16x16 px tile (M=256), N=64 couts, K=64ci in 2 chunks of 32.
// ---------------------------------------------------------------------------
__global__ __launch_bounds__(256, 2)
void conv_kernel(const unsigned short* __restrict__ feats,
                 const unsigned short* __restrict__ wmix,
                 unsigned short* __restrict__ conv_out) {
    __shared__ uint4 sA[1296];         // [18 py][18 px][4 kg] : 18x18 halo x 32 ci
    __shared__ uint4 sW[2304];         // [9 tap][64 co][4 kg] : 32 ci
    int tile = blockIdx.x, sub = blockIdx.y, b = blockIdx.z;
    int y0 = (tile >> 2) * 16, x0 = (tile & 3) * 16;
    int t = threadIdx.x, w = t >> 6, l = t & 63;
    int l16 = l & 15, kg = l >> 4;
    const uint4* fch = (const uint4*)feats + (size_t)(b * 4 + sub) * 32768;
    const uint4* wch = (const uint4*)wmix + (size_t)(b * 4 + sub) * 4608;

    f32x4 acc[4][4];
    #pragma unroll
    for (int r = 0; r < 4; ++r)
        #pragma unroll
        for (int nn = 0; nn < 4; ++nn)
            acc[r][nn] = (f32x4){0.f, 0.f, 0.f, 0.f};

    #pragma unroll
    for (int ck8 = 0; ck8 < 8; ck8 += 4) {   // ci chunk offset in 16B units: {0,4}
        __syncthreads();
        for (int e = t; e < 1296; e += 256) {
            int py = e / 72, rr = e - py * 72, px = rr >> 2, g = rr & 3;
            int gy = y0 - 1 + py, gx = x0 - 1 + px;
            uint4 v = make_uint4(0u, 0u, 0u, 0u);
            if ((unsigned)gy < 64u && (unsigned)gx < 64u)
                v = fch[(gy * 64 + gx) * 8 + ck8 + g];
            sA[e] = v;
        }
        for (int e = t; e < 2304; e += 256) {
            int tap = e >> 8, co = (e >> 2) & 63, g = e & 3;
            sW[e] = wch[tap * 512 + co * 8 + ck8 + g];
        }
        __syncthreads();
        #pragma unroll
        for (int tap = 0; tap < 9; ++tap) {
            int dy = tap / 3, dx = tap - dy * 3;
            bf16x8 bfr[4];
            #pragma unroll
            for (int nn = 0; nn < 4; ++nn)
                bfr[nn] = as_bf16x8(sW[tap * 256 + (nn * 16 + l16) * 4 + kg]);
            #pragma unroll
            for (int r = 0; r < 4; ++r) {
                bf16x8 af = as_bf16x8(sA[((w * 4 + r + dy) * 18 + l16 + dx) * 4 + kg]);
                #pragma unroll
                for (int nn = 0; nn < 4; ++nn)
                    acc[r][nn] = __builtin_amdgcn_mfma_f32_16x16x32_bf16(
                        af, bfr[nn], acc[r][nn], 0, 0, 0);
            }
        }
    }
    // epilogue: D row=(lane>>4)*4+reg is the x-offset, col=lane&15 is cout
    size_t obase = (size_t)(b * 4 + sub) * 262144;
    #pragma unroll
    for (int r = 0; r < 4; ++r) {
        int yy = y0 + w * 4 + r;
        #pragma unroll
        for (int nn = 0; nn < 4; ++nn) {
            int co = nn * 16 + l16;
            #pragma unroll
            for (int j = 0; j < 4; ++j) {
                int xx = x0 + kg * 4 + j;
                conv_out[obase + ((size_t)yy * 64 + xx) * 64 + co] = bf16bits(acc[r][nn][j]);
            }
        }
    }
}

// ---------------------------------------------------------------------------
// K4: Haar IDWT: conv_out[b][sub][y][x][co] bf16 -> out[b][co][Y][X] f32
// grid (64 y, 8 b), 256 threads. LDS transpose.
// ---------------------------------------------------------------------------
__global__ __launch_bounds__(256)
void idwt_kernel(const unsigned short* __restrict__ conv_out,
                 float* __restrict__ out) {
    __shared__ uint4 sT[2304];         // [sub][x][9 chunks] (8 used = 64 c)
    int y = blockIdx.x, b = blockIdx.y;
    int t = threadIdx.x;
    const uint4* cch = (const uint4*)conv_out;
    for (int e = t; e < 2048; e += 256) {
        int s = e >> 9, xx = (e >> 3) & 63, ck = e & 7;
        sT[s * 576 + xx * 9 + ck] = cch[(size_t)(b * 4 + s) * 32768 + y * 512 + xx * 8 + ck];
    }
    __syncthreads();
    int xx = t & 63, cw = t >> 6;
    #pragma unroll
    for (int half = 0; half < 2; ++half) {
        int ckk = half * 4 + cw;       // c chunk 0..7
        bf16x8 v0 = as_bf16x8(sT[0 * 576 + xx * 9 + ckk]);
        bf16x8 v1 = as_bf16x8(sT[1 * 576 + xx * 9 + ckk]);
        bf16x8 v2 = as_bf16x8(sT[2 * 576 + xx * 9 + ckk]);
        bf16x8 v3 = as_bf16x8(sT[3 * 576 + xx * 9 + ckk]);
        #pragma unroll
        for (int j = 0; j < 8; ++j) {
            int c = ckk * 8 + j;
            float ll = (float)v0[j], h0 = (float)v1[j];
            float h1 = (float)v2[j], hh = (float)v3[j];
            float a = (ll + h0 + h1 + hh) * 0.5f;
            float bb = (ll + h0 - h1 - hh) * 0.5f;
            float cc = (ll - h0 + h1 - hh) * 0.5f;
            float dd = (ll - h0 - h1 + hh) * 0.5f;
            float2* o0 = (float2*)out + ((size_t)(b * 64 + c) * 128 + 2 * y) * 64 + xx;
            o0[0]  = make_float2(a, bb);
            o0[64] = make_float2(cc, dd);
        }
    }
}

// ---------------------------------------------------------------------------
extern "C" void kernel_launch(void* const* d_in, const int* in_sizes, int n_in,
                              void* d_out, int out_size, void* d_ws, size_t ws_size,
                              hipStream_t stream) {
    const float* x  = (const float*)d_in[0];
    const float* wt = (const float*)d_in[1];
    const float* aw = (const float*)d_in[2];
    const float* ab = (const float*)d_in[3];
    float* out = (float*)d_out;
    char* ws = (char*)d_ws;

    float* sums              = (float*)ws;                        // 8192 B
    unsigned short* feats    = (unsigned short*)(ws + 8192);      // 16,777,216 B
    unsigned short* wmix     = (unsigned short*)(ws + 8192 + 16777216);        // 2,359,296 B
    unsigned short* conv_out = (unsigned short*)(ws + 8192 + 16777216 + 2359296); // 16,777,216 B

    hipMemsetAsync(sums, 0, 8192, stream);
    hipLaunchKernelGGL(dwt_kernel, dim3(64, 8), dim3(256), 0, stream, x, feats, sums);
    hipLaunchKernelGGL(mix_kernel, dim3(64, 4), dim3(256), 0, stream, wt, aw, ab, sums, wmix);
    hipLaunchKernelGGL(conv_kernel, dim3(16, 4, 8), dim3(256), 0, stream, feats, wmix, conv_out);
    hipLaunchKernelGGL(idwt_kernel, dim3(64, 8), dim3(256), 0, stream, conv_out, out);
}

// Round 4
// 133.477 us; speedup vs baseline: 4.9181x; 1.0067x over previous
//
#include <hip/hip_runtime.h>
#include <hip/hip_bf16.h>
#include <math.h>

// Shapes: x(8,64,128,128) f32; wt(4,4,64,64,3,3) f32; attn_w(4,64); attn_b(4)
// Subband space: 64x64, 4 subbands, 64 cin, 64 cout.

typedef __bf16 bf16x8 __attribute__((ext_vector_type(8)));
typedef float f32x4 __attribute__((ext_vector_type(4)));

__device__ __forceinline__ bf16x8 as_bf16x8(uint4 u) {
    union { uint4 a; bf16x8 b; } c; c.a = u; return c.b;
}
__device__ __forceinline__ unsigned short bf16bits(float f) {
    __hip_bfloat16 h = __float2bfloat16(f);
    union { __hip_bfloat16 h; unsigned short u; } c; c.h = h; return c.u;
}

// ---------------------------------------------------------------------------
// K1: Haar DWT -> bf16 feats[b][sub][y][x][c] + per-y partial logits
//     plog[b][sub][k][y] (no atomics, no zero-init needed).
// grid (64 y, 8 b), 256 threads.
// ---------------------------------------------------------------------------
__global__ __launch_bounds__(256)
void dwt_kernel(const float* __restrict__ x, const float* __restrict__ attn_w,
                unsigned short* __restrict__ feats, float* __restrict__ plog) {
    __shared__ uint4 sT[2304];                     // 4 sub * 64 x * 9 chunks (72 bf16)
    __shared__ float sred[64][4];                  // [c][sub] per-block channel sums
    unsigned short* sTu = (unsigned short*)sT;
    int y = blockIdx.x, b = blockIdx.y;
    int t = threadIdx.x;
    int c = t >> 2, q = t & 3;

    const float4* r0 = (const float4*)x + ((size_t)(b * 64 + c) * 128 + 2 * y) * 32;
    const float4* r1 = r0 + 32;                    // next image row

    float s0 = 0.f, s1 = 0.f, s2 = 0.f, s3 = 0.f;
    #pragma unroll
    for (int i = 0; i < 8; ++i) {
        int f = i * 4 + q;                         // quad covers 4 consecutive float4
        float4 p = r0[f], qq = r1[f];
        int xo = 2 * f;
        {
            float a = p.x, bb = p.y, cc = qq.x, dd = qq.y;
            float ll = (a + bb + cc + dd) * 0.5f, h0 = (a + bb - cc - dd) * 0.5f;
            float h1 = (a - bb + cc - dd) * 0.5f, hh = (a - bb - cc + dd) * 0.5f;
            s0 += ll; s1 += h0; s2 += h1; s3 += hh;
            sTu[0 * 4608 + xo * 72 + c] = bf16bits(ll);
            sTu[1 * 4608 + xo * 72 + c] = bf16bits(h0);
            sTu[2 * 4608 + xo * 72 + c] = bf16bits(h1);
            sTu[3 * 4608 + xo * 72 + c] = bf16bits(hh);
        }
        {
            float a = p.z, bb = p.w, cc = qq.z, dd = qq.w;
            float ll = (a + bb + cc + dd) * 0.5f, h0 = (a + bb - cc - dd) * 0.5f;
            float h1 = (a - bb + cc - dd) * 0.5f, hh = (a - bb - cc + dd) * 0.5f;
            s0 += ll; s1 += h0; s2 += h1; s3 += hh;
            sTu[0 * 4608 + (xo + 1) * 72 + c] = bf16bits(ll);
            sTu[1 * 4608 + (xo + 1) * 72 + c] = bf16bits(h0);
            sTu[2 * 4608 + (xo + 1) * 72 + c] = bf16bits(h1);
            sTu[3 * 4608 + (xo + 1) * 72 + c] = bf16bits(hh);
        }
    }
    // reduce over q (4 consecutive lanes share c) -> sred[c][sub]
    s0 += __shfl_xor(s0, 1); s0 += __shfl_xor(s0, 2);
    s1 += __shfl_xor(s1, 1); s1 += __shfl_xor(s1, 2);
    s2 += __shfl_xor(s2, 1); s2 += __shfl_xor(s2, 2);
    s3 += __shfl_xor(s3, 1); s3 += __shfl_xor(s3, 2);
    if (q == 0) { sred[c][0] = s0; sred[c][1] = s1; sred[c][2] = s2; sred[c][3] = s3; }
    __syncthreads();
    // per-y partial logits (16 threads; others proceed to feats write)
    if (t < 16) {
        int sub = t >> 2, k = t & 3;
        float acc = 0.f;
        #pragma unroll 8
        for (int cc = 0; cc < 64; ++cc)
            acc += attn_w[k * 64 + cc] * sred[cc][sub];
        plog[((size_t)(b * 4 + sub) * 4 + k) * 64 + y] = acc;
    }
    // coalesced channel-last global writes (16B/lane)
    uint4* fch = (uint4*)feats;
    for (int e = t; e < 2048; e += 256) {
        int s = e >> 9, xx = (e >> 3) & 63, ck = e & 7;
        fch[(size_t)((b * 4 + s) * 64 + y) * 512 + xx * 8 + ck] = sT[s * 576 + xx * 9 + ck];
    }
}

// ---------------------------------------------------------------------------
// K2: attention (from plog) + kernel mixing -> bf16 wmix[b][sub][tap][co][ci]
// grid (64 co, 4 sub), 256 threads.
// ---------------------------------------------------------------------------
__global__ __launch_bounds__(256)
void mix_kernel(const float* __restrict__ wt, const float* __restrict__ attn_b,
                const float* __restrict__ plog, unsigned short* __restrict__ wmix) {
    __shared__ float sLw[4][576];       // [k][ci*9+tap]
    __shared__ float satt[8][4];        // [b][k]
    int co = blockIdx.x, sub = blockIdx.y;
    int t = threadIdx.x;

    // attention for all 8 b of this sub (first 32 lanes of wave 0)
    if (t < 32) {
        int b = t >> 2, k = t & 3;
        const float* pp = plog + ((size_t)(b * 4 + sub) * 4 + k) * 64;
        float acc = 0.f;
        #pragma unroll 8
        for (int yy = 0; yy < 64; ++yy) acc += pp[yy];
        float logit = acc * (1.0f / 4096.0f) + attn_b[k];
        float m = fmaxf(logit, __shfl_xor(logit, 1));
        m = fmaxf(m, __shfl_xor(m, 2));
        float e = expf(logit - m);
        float s = e + __shfl_xor(e, 1);
        s += __shfl_xor(s, 2);
        satt[b][k] = e / s;
    }
    // stage wt[k][sub][co][:][:] for k=0..3 (contiguous 576-f32 runs, coalesced)
    for (int e = t; e < 2304; e += 256) {
        int k = e / 576, r = e - k * 576;
        sLw[k][r] = wt[((size_t)(k * 4 + sub) * 64 + co) * 576 + r];
    }
    __syncthreads();
    // produce all 8 b: 18 outputs/thread, 128B-coalesced bf16 writes.
    #pragma unroll
    for (int j = 0; j < 18; ++j) {
        int idx = j * 256 + t;
        int b = idx / 576;
        int r = idx - b * 576;
        int tap = r >> 6, ci = r & 63;
        int wi = ci * 9 + tap;
        float v = satt[b][0] * sLw[0][wi] + satt[b][1] * sLw[1][wi]
                + satt[b][2] * sLw[2][wi] + satt[b][3] * sLw[3][wi];
        wmix[((size_t)(b * 4 + sub) * 9 + tap) * 4096 + co * 64 + ci] = bf16bits(v);
    }
}

// ---------------------------------------------------------------------------
// K3: fused MFMA conv (all 4 subbands) + Haar IDWT epilogue -> f32 out.
// grid (4 cg, 16 tiles, 8 b) = 512 blocks, 256 threads (4 waves).
// Block: 16x16 subband px (M=256), 16 couts, 4 subs, K=64ci x 9 taps.
// Staging: sub-pairs x 2 ci-chunks of 32 (4 stages). A-frag dy-sliding cache.
// ---------------------------------------------------------------------------
__global__ __launch_bounds__(256, 2)
void conv_idwt_kernel(const unsigned short* __restrict__ feats,
                      const unsigned short* __restrict__ wmix,
                      float* __restrict__ out) {
    __shared__ uint4 sA[2592];         // [2 sub][18 py][18 px][4 kg]
    __shared__ uint4 sW[1152];         // [2 sub][9 tap][16 co][4 kg]
    int cg = blockIdx.x, tile = blockIdx.y, b = blockIdx.z;
    int y0 = (tile >> 2) * 16, x0 = (tile & 3) * 16;
    int t = threadIdx.x, w = t >> 6, l = t & 63;
    int l16 = l & 15, kg = l >> 4;
    int w4 = w * 4;
    const uint4* fchb = (const uint4*)feats + (size_t)b * 131072;  // [sub][y][x][ck]
    const uint4* wchb = (const uint4*)wmix + (size_t)b * 18432;    // [sub][tap][co][ck]

    f32x4 acc[4][4];                   // [sub][r]
    #pragma unroll
    for (int s = 0; s < 4; ++s)
        #pragma unroll
        for (int r = 0; r < 4; ++r)
            acc[s][r] = (f32x4){0.f, 0.f, 0.f, 0.f};

    #pragma unroll
    for (int sp = 0; sp < 2; ++sp) {
        #pragma unroll
        for (int ck8 = 0; ck8 < 8; ck8 += 4) {
            __syncthreads();
            // stage A: 2 subs x 18x18 halo x 32 ci
            for (int e = t; e < 2592; e += 256) {
                int s2 = e / 1296, rr = e - s2 * 1296;
                int py = rr / 72, r2 = rr - py * 72, px = r2 >> 2, g = r2 & 3;
                int gy = y0 - 1 + py, gx = x0 - 1 + px;
                uint4 v = make_uint4(0u, 0u, 0u, 0u);
                if ((unsigned)gy < 64u && (unsigned)gx < 64u)
                    v = fchb[(size_t)(sp * 2 + s2) * 32768 + (gy * 64 + gx) * 8 + ck8 + g];
                sA[e] = v;
            }
            // stage W: 2 subs x 9 taps x 16 co x 32 ci
            for (int e = t; e < 1152; e += 256) {
                int s2 = e / 576, r = e - s2 * 576;
                int tap = r >> 6, co = (r >> 2) & 15, g = r & 3;
                sW[e] = wchb[(size_t)(sp * 2 + s2) * 4608 + tap * 512
                             + (cg * 16 + co) * 8 + ck8 + g];
            }
            __syncthreads();
            #pragma unroll
            for (int s2 = 0; s2 < 2; ++s2) {
                int s = sp * 2 + s2;
                int abase = s2 * 1296;
                // sliding-window A-frag cache over dy
                uint4 af[4][3];
                #pragma unroll
                for (int i = 0; i < 4; ++i)
                    #pragma unroll
                    for (int dx = 0; dx < 3; ++dx)
                        af[i][dx] = sA[abase + ((w4 + i) * 18 + l16 + dx) * 4 + kg];
                #pragma unroll
                for (int dy = 0; dy < 3; ++dy) {
                    if (dy > 0) {
                        #pragma unroll
                        for (int i = 0; i < 3; ++i)
                            #pragma unroll
                            for (int dx = 0; dx < 3; ++dx)
                                af[i][dx] = af[i + 1][dx];
                        #pragma unroll
                        for (int dx = 0; dx < 3; ++dx)
                            af[3][dx] = sA[abase + ((w4 + dy + 3) * 18 + l16 + dx) * 4 + kg];
                    }
                    #pragma unroll
                    for (int dx = 0; dx < 3; ++dx) {
                        uint4 bw = sW[s2 * 576 + (dy * 3 + dx) * 64 + l16 * 4 + kg];
                        bf16x8 bfr = as_bf16x8(bw);
                        #pragma unroll
                        for (int r = 0; r < 4; ++r)
                            acc[s][r] = __builtin_amdgcn_mfma_f32_16x16x32_bf16(
                                as_bf16x8(af[r][dx]), bfr, acc[s][r], 0, 0, 0);
                    }
                }
            }
        }
    }
    // IDWT epilogue: lane holds 4 sub-values at (y,x,co); write f32x4 pairs.
    int co = cg * 16 + l16;
    #pragma unroll
    for (int r = 0; r < 4; ++r) {
        int ys = y0 + w4 + r;
        float* orow = out + ((size_t)(b * 64 + co) * 128 + 2 * ys) * 128 + 2 * x0 + 8 * kg;
        float av[4], bv[4], cv[4], dv[4];
        #pragma unroll
        for (int j = 0; j < 4; ++j) {
            float ll = acc[0][r][j], h0 = acc[1][r][j];
            float h1 = acc[2][r][j], hh = acc[3][r][j];
            av[j] = (ll + h0 + h1 + hh) * 0.5f;
            bv[j] = (ll + h0 - h1 - hh) * 0.5f;
            cv[j] = (ll - h0 + h1 - hh) * 0.5f;
            dv[j] = (ll - h0 - h1 + hh) * 0.5f;
        }
        *(float4*)(orow)           = make_float4(av[0], bv[0], av[1], bv[1]);
        *(float4*)(orow + 4)       = make_float4(av[2], bv[2], av[3], bv[3]);
        *(float4*)(orow + 128)     = make_float4(cv[0], dv[0], cv[1], dv[1]);
        *(float4*)(orow + 132)     = make_float4(cv[2], dv[2], cv[3], dv[3]);
    }
}

// ---------------------------------------------------------------------------
extern "C" void kernel_launch(void* const* d_in, const int* in_sizes, int n_in,
                              void* d_out, int out_size, void* d_ws, size_t ws_size,
                              hipStream_t stream) {
    const float* x  = (const float*)d_in[0];
    const float* wt = (const float*)d_in[1];
    const float* aw = (const float*)d_in[2];
    const float* ab = (const float*)d_in[3];
    float* out = (float*)d_out;
    char* ws = (char*)d_ws;

    float* plog              = (float*)ws;                         // 32,768 B
    unsigned short* feats    = (unsigned short*)(ws + 32768);      // 16,777,216 B
    unsigned short* wmix     = (unsigned short*)(ws + 32768 + 16777216); // 2,359,296 B

    hipLaunchKernelGGL(dwt_kernel, dim3(64, 8), dim3(256), 0, stream, x, aw, feats, plog);
    hipLaunchKernelGGL(mix_kernel, dim3(64, 4), dim3(256), 0, stream, wt, ab, plog, wmix);
    hipLaunchKernelGGL(conv_idwt_kernel, dim3(4, 16, 8), dim3(256), 0, stream,
                       feats, wmix, out);
}